// Round 4
// baseline (3050.767 us; speedup 1.0000x reference)
//
#include <hip/hip_runtime.h>
#include <hip/hip_bf16.h>

typedef short v8s __attribute__((ext_vector_type(8)));
typedef float v4f __attribute__((ext_vector_type(4)));
typedef unsigned int u32;
typedef unsigned short u16;
typedef unsigned long long u64;

// ---------- helpers ----------
__device__ __forceinline__ u16 f2bf(float f) {
    union { float f; u32 u; } x; x.f = f;
    u32 r = x.u + 0x7fffu + ((x.u >> 16) & 1u);   // RNE
    return (u16)(r >> 16);
}
__device__ __forceinline__ float bf2f(u16 s) {
    union { u32 u; float f; } x; x.u = ((u32)s) << 16;
    return x.f;
}
__device__ __forceinline__ float sigmoidf_(float x) { return 1.f / (1.f + __expf(-x)); }
__device__ __forceinline__ float tanh_fast(float x) {
    float t = fminf(fmaxf(x, -15.f), 15.f);
    float e = __expf(2.f * t);
    return (e - 1.f) / (e + 1.f);
}

// ---------- prep kernels ----------
__global__ __launch_bounds__(256) void xbf_kernel(const float* __restrict__ x, u16* __restrict__ xbf, int n) {
    int i = (blockIdx.x * 256 + threadIdx.x) * 4;
    if (i + 3 < n) {
        float4 v = *(const float4*)(x + i);
        u16* d = xbf + i;
        d[0] = f2bf(v.x); d[1] = f2bf(v.y); d[2] = f2bf(v.z); d[3] = f2bf(v.w);
    }
}

// W1[n][tap*2048+d] = n<512 ? wb[n,d,tap] : wr[n-512,d,tap]
// W2[n][tap*2048+d] = n<512 ? wa[n,d,tap] : wr[n-512,d,tap+5]
__global__ __launch_bounds__(256) void packw_kernel(const float* __restrict__ wb, const float* __restrict__ wa,
                                                    const float* __restrict__ wr, u16* __restrict__ W1, u16* __restrict__ W2) {
    long idx = (long)blockIdx.x * 256 + threadIdx.x;        // < 2*1024*10240
    int which = idx >= (1024L * 10240) ? 1 : 0;
    long rem = idx - (long)which * 1024 * 10240;
    int n = (int)(rem / 10240);
    int kap = (int)(rem % 10240);
    int tap = kap >> 11, d = kap & 2047;
    float v;
    if (n < 512) v = which ? wa[(long)n * 10240 + d * 5 + tap] : wb[(long)n * 10240 + d * 5 + tap];
    else         v = wr[(long)(n - 512) * 20480 + d * 10 + tap + (which ? 5 : 0)];
    (which ? W2 : W1)[rem] = f2bf(v);
}

// wihpad[(dir*2048+g)][k] (K padded 513->576)
__global__ __launch_bounds__(256) void packwih_kernel(const float* __restrict__ wf, const float* __restrict__ wr,
                                                      u16* __restrict__ Bp) {
    int idx = blockIdx.x * 256 + threadIdx.x;               // < 4096*576
    int n = idx / 576, kap = idx % 576;
    int dir = n >> 11, g = n & 2047;
    const float* src = dir ? wr : wf;
    float v = (kap < 513) ? src[(long)g * 513 + kap] : 0.f;
    Bp[idx] = f2bf(v);
}

__global__ __launch_bounds__(256) void packwhh_kernel(const float* __restrict__ whf, const float* __restrict__ whr,
                                                      u16* __restrict__ W) {
    int idx = blockIdx.x * 256 + threadIdx.x;               // < 2*2048*512 = 2^21
    int dir = idx >> 20;
    float v = dir ? whr[idx & 1048575] : whf[idx];
    W[idx] = f2bf(v);
}

// bsum + hbuf tag clear (must run every launch: graph replays reuse hbuf)
__global__ __launch_bounds__(256) void misc_kernel(const float* __restrict__ bihf, const float* __restrict__ bhhf,
                                                   const float* __restrict__ bihr, const float* __restrict__ bhhr,
                                                   float* __restrict__ bsum, u64* __restrict__ hbuf) {
    int i = blockIdx.x * 256 + threadIdx.x;                 // grid covers 4096 + 16384
    if (i < 2048) bsum[i] = bihf[i] + bhhf[i];
    else if (i < 4096) bsum[i] = bihr[i - 2048] + bhhr[i - 2048];
    else if (i < 4096 + 16384) hbuf[i - 4096] = 0xFFFFFFFF00000000ULL;
}

// ---------- bf16 GEMM: C(MxN) = A(MxK,bf16; strided rows) * B(NxK,bf16)^T ----------
// row offset (elements) of logical row m: (m/row_div)*row_mul1 + (m%row_div)*row_mul2 + row_base
template <int OUTBF>
__global__ __launch_bounds__(256) void gemm_bf16(const u16* __restrict__ A, const u16* __restrict__ B,
                                                 void* __restrict__ Cv, int M, int N, int K, int ldc,
                                                 int row_div, u32 row_mul1, u32 row_mul2, u32 row_base) {
    __shared__ u16 ldsA[128 * 64];
    __shared__ u16 ldsB[128 * 64];
    const int ntn = N >> 7;
    const int tm = blockIdx.x / ntn, tn = blockIdx.x % ntn;
    const int tid = threadIdx.x, lane = tid & 63, wv = tid >> 6;
    const int wm = wv >> 1, wn = wv & 1;
    const int qbase = wv * 4;

    u32 asrc[4], bsrc[4];
#pragma unroll
    for (int it = 0; it < 4; ++it) {
        int q = qbase + it;
        int r = q * 8 + (lane >> 3);                         // tile row 0..127
        int cb = ((lane & 7) * 16) ^ ((r & 7) << 4);         // logical col byte (XOR-swizzle source)
        int m = tm * 128 + r; if (m > M - 1) m = M - 1;
        asrc[it] = row_base + (u32)(m / row_div) * row_mul1 + (u32)(m % row_div) * row_mul2 + (u32)(cb >> 1);
        int n = tn * 128 + r;
        bsrc[it] = (u32)n * (u32)K + (u32)(cb >> 1);
    }

    v4f acc[4][4];
#pragma unroll
    for (int i = 0; i < 4; ++i)
#pragma unroll
        for (int j = 0; j < 4; ++j) acc[i][j] = (v4f){0.f, 0.f, 0.f, 0.f};

    const int KT = K >> 6;
    for (int kt = 0; kt < KT; ++kt) {
        const int k0 = kt << 6;
#pragma unroll
        for (int it = 0; it < 4; ++it) {
            int q = qbase + it;
            __builtin_amdgcn_global_load_lds(
                (const __attribute__((address_space(1))) u32*)(A + asrc[it] + k0),
                (__attribute__((address_space(3))) u32*)((char*)ldsA + q * 1024), 16, 0, 0);
            __builtin_amdgcn_global_load_lds(
                (const __attribute__((address_space(1))) u32*)(B + bsrc[it] + k0),
                (__attribute__((address_space(3))) u32*)((char*)ldsB + q * 1024), 16, 0, 0);
        }
        __syncthreads();
#pragma unroll
        for (int kk = 0; kk < 2; ++kk) {
            v8s af[4], bfr[4];
#pragma unroll
            for (int i = 0; i < 4; ++i) {
                int row = wm * 64 + i * 16 + (lane & 15);
                int cbyte = (kk * 64 + ((lane >> 4) * 16)) ^ ((row & 7) << 4);
                af[i] = *(const v8s*)((const char*)ldsA + row * 128 + cbyte);
                int rn = wn * 64 + i * 16 + (lane & 15);
                int cbn = (kk * 64 + ((lane >> 4) * 16)) ^ ((rn & 7) << 4);
                bfr[i] = *(const v8s*)((const char*)ldsB + rn * 128 + cbn);
            }
#pragma unroll
            for (int i = 0; i < 4; ++i)
#pragma unroll
                for (int j = 0; j < 4; ++j)
                    acc[i][j] = __builtin_amdgcn_mfma_f32_16x16x32_bf16(af[i], bfr[j], acc[i][j], 0, 0, 0);
        }
        __syncthreads();
    }
#pragma unroll
    for (int i = 0; i < 4; ++i)
#pragma unroll
        for (int j = 0; j < 4; ++j)
#pragma unroll
            for (int r = 0; r < 4; ++r) {
                int m = tm * 128 + wm * 64 + i * 16 + (lane >> 4) * 4 + r;
                int n = tn * 128 + wn * 64 + j * 16 + (lane & 15);
                if (m < M) {
                    if (OUTBF) ((u16*)Cv)[(long)m * ldc + n] = f2bf(acc[i][j][r]);
                    else       ((float*)Cv)[(long)m * ldc + n] = acc[i][j][r];
                }
            }
}

// ---------- combine: build seq (bf16, padded K=576, row = t*16+b) ----------
__global__ __launch_bounds__(256) void combine_kernel(const float* __restrict__ G1, const float* __restrict__ G2,
                                                      const float* __restrict__ bb, const float* __restrict__ ba,
                                                      const float* __restrict__ br, u16* __restrict__ seqpad) {
    int m = blockIdx.x;                    // b*502 + t
    int b = m / 502, t = m % 502;
    int tid = threadIdx.x;
    const float* g1 = G1 + (long)m * 1024;
    const float* g2 = G2 + (long)m * 1024;
    u16* dst = seqpad + (long)(t * 16 + b) * 576;
    float part = 0.f;
#pragma unroll
    for (int rep = 0; rep < 2; ++rep) {
        int u = tid + rep * 256;
        float db = g1[u] + bb[u];
        float da = g2[u] + ba[u];
        part += db * da;
        float vr = g1[512 + u] + g2[512 + u] + br[u];
        dst[u] = f2bf(vr);
    }
#pragma unroll
    for (int off = 32; off; off >>= 1) part += __shfl_down(part, off, 64);
    __shared__ float red[4];
    if ((tid & 63) == 0) red[tid >> 6] = part;
    __syncthreads();
    if (tid == 0) dst[512] = f2bf(red[0] + red[1] + red[2] + red[3]);
    if (tid >= 1 && tid < 64) dst[512 + tid] = 0;
}

// ---------- persistent bidirectional LSTM, both directions interleaved on 16 WGs ----------
// WG j owns units [32j,32j+32) for BOTH dirs. 4 waves = 4 gate types.
// Sync: data-tagged 8B words {h_pair, step}; each dir's visibility latency hides
// under the other dir's compute phase.
__global__ __launch_bounds__(256, 1) void lstm_kernel(const u16* __restrict__ P, const u16* __restrict__ whhbf,
                                                      const float* __restrict__ bsum, u64* hbuf,
                                                      u16* __restrict__ hs) {
    const int j = blockIdx.x;
    const int tid = threadIdx.x, lane = tid & 63, w = tid >> 6;
    __shared__ u16 hls[16 * 512];          // h (batch x 512) bf16, XOR-swizzled rows (reused per phase)
    __shared__ float gls[4][16][32];       // gate type x batch x unit (reused per phase)

    // whh^T fragments for BOTH dirs live in VGPRs all 502 steps (256 VGPRs)
    v8s bf[2][2][16];
#pragma unroll
    for (int d = 0; d < 2; ++d) {
        const u16* whd = whhbf + (long)d * 2048 * 512;
#pragma unroll
        for (int nt = 0; nt < 2; ++nt) {
            int n = w * 512 + j * 32 + nt * 16 + (lane & 15);
#pragma unroll
            for (int kt = 0; kt < 16; ++kt)
                bf[d][nt][kt] = *(const v8s*)(whd + (long)n * 512 + kt * 32 + ((lane >> 4) * 8));
        }
    }
    for (int i = tid; i < 8192; i += 256) hls[i] = 0;   // zero h for s=0 (both phases read zeros at s=0)

    const int b_ = tid >> 4;
    const int u_ = (tid * 2) & 31;
    float cst[2][2] = {{0.f, 0.f}, {0.f, 0.f}};
    u64* hb0 = hbuf;              // dir0: 2 slots x 4096
    u64* hb1 = hbuf + 2 * 4096;   // dir1

    const int col0 = w * 512 + j * 32 + (lane & 15);
    float bs0[2], bs1[2];
    bs0[0] = bsum[col0];        bs1[0] = bsum[col0 + 16];
    bs0[1] = bsum[2048 + col0]; bs1[1] = bsum[2048 + col0 + 16];

    // P prefetch registers (s=0 for both dirs)
    float pv[2][2][4];
#pragma unroll
    for (int d = 0; d < 2; ++d) {
        int tau = d ? 501 : 0;
        const u16* Pd = P + d * 2048;
#pragma unroll
        for (int nt = 0; nt < 2; ++nt)
#pragma unroll
            for (int r = 0; r < 4; ++r)
                pv[d][nt][r] = bf2f(Pd[(long)(tau * 16 + ((lane >> 4) * 4 + r)) * 4096 + col0 + nt * 16]);
    }
    u64 vv0[16], vv1[16];
    __syncthreads();

#define POLL_ISSUE(slot, vv)                                                                        \
    _Pragma("unroll")                                                                               \
    for (int rep = 0; rep < 16; ++rep)                                                              \
        vv[rep] = __hip_atomic_load((slot) + tid + rep * 256, __ATOMIC_RELAXED, __HIP_MEMORY_SCOPE_AGENT);

#define POLL_FINISH_FILL(slot, want, vv)                                                            \
    for (;;) {                                                                                      \
        u32 ok = 0;                                                                                 \
        _Pragma("unroll")                                                                           \
        for (int rep = 0; rep < 16; ++rep) ok += ((u32)(vv[rep] >> 32) == (u32)(want));             \
        if (ok == 16) break;                                                                        \
        POLL_ISSUE(slot, vv)                                                                        \
    }                                                                                               \
    _Pragma("unroll")                                                                               \
    for (int rep = 0; rep < 16; ++rep) {                                                            \
        int i_ = tid + rep * 256;                                                                   \
        int bb_ = i_ >> 8;                                                                          \
        int bo_ = (bb_ << 10) + (((i_ & 255) << 2) ^ ((bb_ & 7) << 4));                             \
        *(u32*)((char*)hls + bo_) = (u32)vv[rep];                                                   \
    }

#define MFMA_PHASE(d)                                                                               \
    v4f a0a, a1a, a0b = (v4f){0, 0, 0, 0}, a1b = (v4f){0, 0, 0, 0};                                 \
    _Pragma("unroll")                                                                               \
    for (int r = 0; r < 4; ++r) { a0a[r] = pv[d][0][r] + bs0[d]; a1a[r] = pv[d][1][r] + bs1[d]; }   \
    _Pragma("unroll")                                                                               \
    for (int kt = 0; kt < 16; kt += 2) {                                                            \
        int row = lane & 15;                                                                        \
        int cb0 = (kt * 64 + ((lane >> 4) * 16)) ^ ((row & 7) << 4);                                \
        int cb1 = ((kt + 1) * 64 + ((lane >> 4) * 16)) ^ ((row & 7) << 4);                          \
        v8s af0 = *(const v8s*)((const char*)hls + row * 1024 + cb0);                               \
        v8s af1 = *(const v8s*)((const char*)hls + row * 1024 + cb1);                               \
        a0a = __builtin_amdgcn_mfma_f32_16x16x32_bf16(af0, bf[d][0][kt], a0a, 0, 0, 0);             \
        a1a = __builtin_amdgcn_mfma_f32_16x16x32_bf16(af0, bf[d][1][kt], a1a, 0, 0, 0);             \
        a0b = __builtin_amdgcn_mfma_f32_16x16x32_bf16(af1, bf[d][0][kt + 1], a0b, 0, 0, 0);         \
        a1b = __builtin_amdgcn_mfma_f32_16x16x32_bf16(af1, bf[d][1][kt + 1], a1b, 0, 0, 0);         \
    }                                                                                               \
    _Pragma("unroll")                                                                               \
    for (int r = 0; r < 4; ++r) {                                                                   \
        gls[w][(lane >> 4) * 4 + r][(lane & 15)] = a0a[r] + a0b[r];                                 \
        gls[w][(lane >> 4) * 4 + r][16 + (lane & 15)] = a1a[r] + a1b[r];                            \
    }

#define GATES_PHASE(d, hbd, s_, tau_)                                                               \
    {                                                                                               \
        float gi0 = gls[0][b_][u_],     gf0 = gls[1][b_][u_],     gg0 = gls[2][b_][u_],     go0 = gls[3][b_][u_];     \
        float gi1 = gls[0][b_][u_ + 1], gf1 = gls[1][b_][u_ + 1], gg1 = gls[2][b_][u_ + 1], go1 = gls[3][b_][u_ + 1]; \
        cst[d][0] = sigmoidf_(gf0) * cst[d][0] + sigmoidf_(gi0) * tanh_fast(gg0);                   \
        cst[d][1] = sigmoidf_(gf1) * cst[d][1] + sigmoidf_(gi1) * tanh_fast(gg1);                   \
        float h0 = sigmoidf_(go0) * tanh_fast(cst[d][0]);                                           \
        float h1 = sigmoidf_(go1) * tanh_fast(cst[d][1]);                                           \
        u32 hw = (u32)f2bf(h0) | ((u32)f2bf(h1) << 16);                                             \
        int gi_ = (b_ * 512 + j * 32 + u_) >> 1;                                                    \
        __hip_atomic_store(hbd + ((s_) & 1) * 4096 + gi_, (u64)hw | ((u64)(u32)(s_) << 32),         \
                           __ATOMIC_RELAXED, __HIP_MEMORY_SCOPE_AGENT);                             \
        *(u32*)(hs + (((long)((d) * 502 + (tau_)) * 16 + b_) * 512 + j * 32 + u_)) = hw;            \
        if ((s_) + 1 < 502) {                                                                       \
            int tau2 = (d) ? (500 - (s_)) : ((s_) + 1);                                             \
            const u16* Pd = P + (d) * 2048;                                                         \
            _Pragma("unroll")                                                                       \
            for (int nt = 0; nt < 2; ++nt)                                                          \
                _Pragma("unroll")                                                                   \
                for (int r = 0; r < 4; ++r)                                                         \
                    pv[d][nt][r] = bf2f(Pd[(long)(tau2 * 16 + ((lane >> 4) * 4 + r)) * 4096 + col0 + nt * 16]); \
        }                                                                                           \
    }

    for (int s = 0; s < 502; ++s) {
        // ================= PHASE 0 : dir 0 =================
        if (s > 0) {
            u64* slot0 = hb0 + ((s - 1) & 1) * 4096;
            POLL_FINISH_FILL(slot0, s - 1, vv0)
        }
        __syncthreads();                                   // B1: hls(d0) ready
        { MFMA_PHASE(0) }
        __syncthreads();                                   // B2: gls(d0) ready
        if (s > 0) { u64* slot1 = hb1 + ((s - 1) & 1) * 4096; POLL_ISSUE(slot1, vv1) }
        GATES_PHASE(0, hb0, s, s)
        // ================= PHASE 1 : dir 1 =================
        if (s > 0) {
            u64* slot1 = hb1 + ((s - 1) & 1) * 4096;
            POLL_FINISH_FILL(slot1, s - 1, vv1)
        }
        __syncthreads();                                   // B3: hls(d1) ready (also: gls d0 fully read)
        { MFMA_PHASE(1) }
        __syncthreads();                                   // B4: gls(d1) ready
        if (s + 1 < 502) { u64* slot0 = hb0 + (s & 1) * 4096; POLL_ISSUE(slot0, vv0) }
        GATES_PHASE(1, hb1, s, 501 - s)
    }
#undef POLL_ISSUE
#undef POLL_FINISH_FILL
#undef MFMA_PHASE
#undef GATES_PHASE
}

// ---------- final FC + sigmoid ----------
__global__ __launch_bounds__(256) void final_kernel(const u16* __restrict__ hs, const float* __restrict__ wfc,
                                                    const float* __restrict__ bfc, float* __restrict__ out) {
    int m = blockIdx.x;                    // t*16 + b
    int t = m >> 4, b = m & 15;
    int tid = threadIdx.x;
    const u16* hf = hs + ((long)t * 16 + b) * 512;
    const u16* hr = hs + ((long)(502 + t) * 16 + b) * 512;
    float part = 0.f;
#pragma unroll
    for (int rep = 0; rep < 2; ++rep) {
        int u = tid + rep * 256;
        part += bf2f(hf[u]) * wfc[u] + bf2f(hr[u]) * wfc[512 + u];
    }
#pragma unroll
    for (int off = 32; off; off >>= 1) part += __shfl_down(part, off, 64);
    __shared__ float red[4];
    if ((tid & 63) == 0) red[tid >> 6] = part;
    __syncthreads();
    if (tid == 0) {
        float lg = red[0] + red[1] + red[2] + red[3] + bfc[0];
        out[(long)b * 502 + t] = 1.f / (1.f + __expf(-lg));
    }
}

// ---------- launch ----------
extern "C" void kernel_launch(void* const* d_in, const int* in_sizes, int n_in,
                              void* d_out, int out_size, void* d_ws, size_t ws_size,
                              hipStream_t stream) {
    const float* x     = (const float*)d_in[0];
    const float* wb    = (const float*)d_in[1];
    const float* bb    = (const float*)d_in[2];
    const float* wa    = (const float*)d_in[3];
    const float* ba    = (const float*)d_in[4];
    const float* wr    = (const float*)d_in[5];
    const float* br    = (const float*)d_in[6];
    const float* wih_f = (const float*)d_in[7];
    const float* whh_f = (const float*)d_in[8];
    const float* bih_f = (const float*)d_in[9];
    const float* bhh_f = (const float*)d_in[10];
    const float* wih_r = (const float*)d_in[11];
    const float* whh_r = (const float*)d_in[12];
    const float* bih_r = (const float*)d_in[13];
    const float* bhh_r = (const float*)d_in[14];
    const float* wfc   = (const float*)d_in[15];
    const float* bfc   = (const float*)d_in[16];
    float* out = (float*)d_out;

    char* ws = (char*)d_ws;
    // Region 1 (75,497,472 B): xbf | W1 | W2  -> dead after conv GEMMs, reused for Pb (65,798,144 B)
    u16* xbf = (u16*)ws;
    u16* W1  = (u16*)(ws + 33554432);
    u16* W2  = (u16*)(ws + 54525952);
    u16* Pb  = (u16*)ws;
    // Region 2 (65,798,144 B): G1 | G2 -> dead after combine, reused for hs (16,449,536 B)
    char* r2 = ws + 75497472;
    float* G1 = (float*)r2;
    float* G2 = (float*)(r2 + 32899072);
    u16*  hs  = (u16*)r2;
    // Region 3 (~18.3 MB): persistent smalls
    char* r3 = r2 + 65798144;
    u16*  seqp = (u16*)r3;                    //  9,252,864
    u16*  wihp = (u16*)(r3 + 9252864);        //  4,718,592
    u16*  whhb = (u16*)(r3 + 13971456);       //  4,194,304
    float* bsum= (float*)(r3 + 18165760);     //     16,384
    u64*  hbuf = (u64*)(r3 + 18182144);       //    131,072 (2 dir x 2 slot x 4096 x 8B)
    // total ~159.6 MB

    // prep
    xbf_kernel<<<16384, 256, 0, stream>>>(x, xbf, 16 * 512 * 2048);
    packw_kernel<<<81920, 256, 0, stream>>>(wb, wa, wr, W1, W2);
    packwih_kernel<<<9216, 256, 0, stream>>>(wih_f, wih_r, wihp);
    packwhh_kernel<<<8192, 256, 0, stream>>>(whh_f, whh_r, whhb);
    misc_kernel<<<80, 256, 0, stream>>>(bih_f, bhh_f, bih_r, bhh_r, bsum, hbuf);

    // conv GEMMs: M=8032 (b*502+t), K=10240, N=1024
    gemm_bf16<0><<<63 * 8, 256, 0, stream>>>(xbf, W1, G1, 8032, 1024, 10240, 1024,
                                             502, 512u * 2048u, 2048u, 0u);
    gemm_bf16<0><<<63 * 8, 256, 0, stream>>>(xbf, W2, G2, 8032, 1024, 10240, 1024,
                                             502, 512u * 2048u, 2048u, 5u * 2048u);
    // seq build
    combine_kernel<<<8032, 256, 0, stream>>>(G1, G2, bb, ba, br, seqp);
    // input projections: M=8032 (t*16+b), K=576, N=4096 -> bf16 P (overwrites region 1)
    gemm_bf16<1><<<63 * 32, 256, 0, stream>>>(seqp, wihp, Pb, 8032, 4096, 576, 4096,
                                              8032, 0u, 576u, 0u);
    // recurrence: both dirs interleaved on 16 WGs
    lstm_kernel<<<16, 256, 0, stream>>>(Pb, whhb, bsum, hbuf, hs);
    // output
    final_kernel<<<8032, 256, 0, stream>>>(hs, wfc, bfc, out);
}